// Round 1
// baseline (193.948 us; speedup 1.0000x reference)
//
#include <hip/hip_runtime.h>

// B=64, L=512, D=768, V=100
// summed[b,l,:] = w0s * pooler[b,l,:] + w1s * xt[b,:]
//   xt[b,d] = e0*W[0,d] + e1*W[1,d] + b_dense[d],  (e0,e1) = emb_table[ids[b]]
//   s00 = p.p (per row), s01 = p.xt (per row), s11 = xt.xt (per b!)
//   S0 = sum(p) (per row), S1 = sum(xt) (per b!)
//   row0 softmax over (s00,s01), row1 softmax over (s01,s11); w = column sums
// LayerNorm closed form from (S0,S1,s00,s01,s11).
//
// R1: 256-thread blocks (4 waves) — fixes workgroup-slot occupancy limit.
// R2: NT store via native clang vector type (compile fix).
// R3: 4 rows per wave, same-b block (16 rows/block, 16|512 so single b).
//     Hoist per-b/per-lane invariants into registers ONCE per wave:
//     xt[3], gamma[3], beta[3], s11, S1. Steady-state per row drops from
//     18 VMEM loads + 5-value butterfly to 3 loads + 3-value butterfly +
//     3 NT stores. Unrolled row loop overlaps the 4 independent reduction
//     chains and keeps 12 pooler loads in flight per wave.

constexpr int Bc = 64;
constexpr int Lc = 512;
constexpr int Dc = 768;            // = 192 float4 = 3 float4 per lane (wave64)
constexpr float LN_EPS = 1e-6f;
constexpr int WAVES_PER_BLOCK = 4;
constexpr int ROWS_PER_WAVE   = 4;
constexpr int ROWS_PER_BLOCK  = WAVES_PER_BLOCK * ROWS_PER_WAVE;  // 16

typedef float nv_float4 __attribute__((ext_vector_type(4)));

__global__ __launch_bounds__(64 * WAVES_PER_BLOCK) void hier_attn_ln_kernel(
    const int*   __restrict__ ids,        // (B,1)
    const float* __restrict__ pooler,     // (B,L,D)
    const float* __restrict__ emb_table,  // (V,2)
    const float* __restrict__ W,          // (2,D)
    const float* __restrict__ bvec,       // (D,)
    const float* __restrict__ gamma,      // (D,)
    const float* __restrict__ beta,       // (D,)
    float*       __restrict__ out)        // (B,L,D)
{
    const int wave = threadIdx.x >> 6;
    const int lane = threadIdx.x & 63;
    const int row0 = blockIdx.x * ROWS_PER_BLOCK + wave * ROWS_PER_WAVE;
    const int b    = row0 >> 9;                       // L = 512; 16|512 -> one b/block

    const float4* W0_4 = (const float4*)W;
    const float4* W1_4 = (const float4*)(W + Dc);
    const float4* b_4  = (const float4*)bvec;
    const float4* g_4  = (const float4*)gamma;
    const float4* be_4 = (const float4*)beta;

    const int id = ids[b];
    const float e0 = emb_table[id * 2 + 0];
    const float e1 = emb_table[id * 2 + 1];

    // ---- per-wave prologue: build xt, load gamma/beta, reduce s11/S1 ----
    float4 xt[3], gm[3], bt[3];
    float s11 = 0.f, S1 = 0.f;
#pragma unroll
    for (int j = 0; j < 3; ++j) {
        const int idx4 = lane + j * 64;               // coalesced across wave
        float4 w0 = W0_4[idx4];
        float4 w1 = W1_4[idx4];
        float4 bd = b_4[idx4];
        gm[j] = g_4[idx4];
        bt[j] = be_4[idx4];
        float4 x;
        x.x = fmaf(e0, w0.x, fmaf(e1, w1.x, bd.x));
        x.y = fmaf(e0, w0.y, fmaf(e1, w1.y, bd.y));
        x.z = fmaf(e0, w0.z, fmaf(e1, w1.z, bd.z));
        x.w = fmaf(e0, w0.w, fmaf(e1, w1.w, bd.w));
        xt[j] = x;
        s11 += x.x*x.x + x.y*x.y + x.z*x.z + x.w*x.w;
        S1  += x.x + x.y + x.z + x.w;
    }
#pragma unroll
    for (int off = 32; off > 0; off >>= 1) {
        s11 += __shfl_xor(s11, off);
        S1  += __shfl_xor(S1,  off);
    }

    const float invD = 1.f / (float)Dc;
    const float4* p_base = (const float4*)(pooler + (size_t)row0 * Dc);
    nv_float4*    o_base = (nv_float4*)(out + (size_t)row0 * Dc);

    // ---- steady-state: 4 rows, 3 loads + 3-value butterfly + 3 stores ----
#pragma unroll
    for (int r = 0; r < ROWS_PER_WAVE; ++r) {
        const float4* prow4 = p_base + (size_t)r * (Dc / 4);
        nv_float4*    orow4 = o_base + (size_t)r * (Dc / 4);

        float4 t0[3];
        float s00 = 0.f, s01 = 0.f, S0 = 0.f;
#pragma unroll
        for (int j = 0; j < 3; ++j) {
            float4 p = prow4[lane + j * 64];
            t0[j] = p;
            s00 += p.x*p.x + p.y*p.y + p.z*p.z + p.w*p.w;
            s01 += p.x*xt[j].x + p.y*xt[j].y + p.z*xt[j].z + p.w*xt[j].w;
            S0  += p.x + p.y + p.z + p.w;
        }
#pragma unroll
        for (int off = 32; off > 0; off >>= 1) {
            s00 += __shfl_xor(s00, off);
            s01 += __shfl_xor(s01, off);
            S0  += __shfl_xor(S0,  off);
        }

        // Two 2-way softmaxes (max-subtracted: s00 ~ O(768), naive exp overflows).
        const float m0  = fmaxf(s00, s01);
        const float a00 = __expf(s00 - m0);
        const float a01 = __expf(s01 - m0);
        const float r0  = 1.f / (a00 + a01);
        const float m1  = fmaxf(s01, s11);
        const float a10 = __expf(s01 - m1);
        const float a11 = __expf(s11 - m1);
        const float r1  = 1.f / (a10 + a11);
        const float w0s = a00 * r0 + a10 * r1;        // weight on pooler
        const float w1s = a01 * r0 + a11 * r1;        // weight on xt

        const float mean = (w0s * S0 + w1s * S1) * invD;
        const float ex2  = (w0s*w0s*s00 + 2.f*w0s*w1s*s01 + w1s*w1s*s11) * invD;
        const float var  = ex2 - mean * mean;
        const float rstd = rsqrtf(var + LN_EPS);

        // Fold: (w0s*p + w1s*xt - mean)*rstd*gm + bt
        //     = (a*p + (c*xt - m))*gm + bt   with a,c,m pre-scaled by rstd
        const float a = w0s * rstd;
        const float c = w1s * rstd;
        const float m = mean * rstd;

#pragma unroll
        for (int j = 0; j < 3; ++j) {
            nv_float4 o;
            o.x = fmaf(gm[j].x, fmaf(a, t0[j].x, fmaf(c, xt[j].x, -m)), bt[j].x);
            o.y = fmaf(gm[j].y, fmaf(a, t0[j].y, fmaf(c, xt[j].y, -m)), bt[j].y);
            o.z = fmaf(gm[j].z, fmaf(a, t0[j].z, fmaf(c, xt[j].z, -m)), bt[j].z);
            o.w = fmaf(gm[j].w, fmaf(a, t0[j].w, fmaf(c, xt[j].w, -m)), bt[j].w);
            __builtin_nontemporal_store(o, &orow4[lane + j * 64]);
        }
    }
}

extern "C" void kernel_launch(void* const* d_in, const int* in_sizes, int n_in,
                              void* d_out, int out_size, void* d_ws, size_t ws_size,
                              hipStream_t stream) {
    const int*   ids       = (const int*)  d_in[0];
    const float* pooler    = (const float*)d_in[1];
    const float* emb_table = (const float*)d_in[2];
    const float* W_dense   = (const float*)d_in[3];
    const float* b_dense   = (const float*)d_in[4];
    const float* gamma     = (const float*)d_in[5];
    const float* beta      = (const float*)d_in[6];
    float* out = (float*)d_out;

    const int nrows = Bc * Lc;  // 32768
    hipLaunchKernelGGL(hier_attn_ln_kernel,
                       dim3(nrows / ROWS_PER_BLOCK), dim3(64 * WAVES_PER_BLOCK),
                       0, stream,
                       ids, pooler, emb_table, W_dense, b_dense, gamma, beta, out);
}

// Round 2
// 192.095 us; speedup vs baseline: 1.0096x; 1.0096x over previous
//
#include <hip/hip_runtime.h>

// B=64, L=512, D=768, V=100
// summed[b,l,:] = w0s * pooler[b,l,:] + w1s * xt[b,:]
//   xt[b,d] = e0*W[0,d] + e1*W[1,d] + b_dense[d],  (e0,e1) = emb_table[ids[b]]
//   s00 = p.p (per row), s01 = p.xt (per row), s11 = xt.xt (per b)
//   S0 = sum(p) (per row), S1 = sum(xt) (per b)
//   row0 softmax over (s00,s01), row1 softmax over (s01,s11); w = column sums
// LayerNorm closed form from (S0,S1,s00,s01,s11).
//
// R1: 256-thread blocks (4 waves) — workgroup-slot occupancy fix.
// R2: NT store via native clang vector type.
// R3: 4 rows/wave, per-b invariants (xt,s11,S1) hoisted. REGRESSED 58->65us:
//     VALUBusy 14%/HBM 29%/Occ 31% = latency-bound. VGPR=60 shows compiler
//     serialized the row loop (no pipelining): 3 loads -> wait -> 6-step
//     butterfly -> exp -> store per row, ~nothing in flight.
// R4: restore MLP explicitly. Issue ALL 12 pooler loads up front (t[4][3],
//     48 VGPR), butterfly as 12 interleaved chains (6-step latency amortized
//     over 12 values, not per-row), gamma/beta loads deferred to epilogue
//     (L1/L2-hot broadcast; latency hides under 4 indep softmax chains).
//     ~130 VGPR -> 4 waves/SIMD; 16 waves x 12KB loads in flight >> 10KB
//     Little's-law need at 6.3 TB/s.

constexpr int Bc = 64;
constexpr int Lc = 512;
constexpr int Dc = 768;            // = 192 float4 = 3 float4 per lane (wave64)
constexpr float LN_EPS = 1e-6f;
constexpr int WAVES_PER_BLOCK = 4;
constexpr int ROWS_PER_WAVE   = 4;
constexpr int ROWS_PER_BLOCK  = WAVES_PER_BLOCK * ROWS_PER_WAVE;  // 16

typedef float nv_float4 __attribute__((ext_vector_type(4)));

__global__ __launch_bounds__(64 * WAVES_PER_BLOCK) void hier_attn_ln_kernel(
    const int*   __restrict__ ids,        // (B,1)
    const float* __restrict__ pooler,     // (B,L,D)
    const float* __restrict__ emb_table,  // (V,2)
    const float* __restrict__ W,          // (2,D)
    const float* __restrict__ bvec,       // (D,)
    const float* __restrict__ gamma,      // (D,)
    const float* __restrict__ beta,       // (D,)
    float*       __restrict__ out)        // (B,L,D)
{
    const int wave = threadIdx.x >> 6;
    const int lane = threadIdx.x & 63;
    const int row0 = blockIdx.x * ROWS_PER_BLOCK + wave * ROWS_PER_WAVE;
    const int b    = row0 >> 9;                       // L = 512; 16|512 -> one b/block

    const float4* W0_4 = (const float4*)W;
    const float4* W1_4 = (const float4*)(W + Dc);
    const float4* b_4  = (const float4*)bvec;
    const float4* g_4  = (const float4*)gamma;
    const float4* be_4 = (const float4*)beta;

    const int id = ids[b];
    const float e0 = emb_table[id * 2 + 0];
    const float e1 = emb_table[id * 2 + 1];

    const float4* p_base = (const float4*)(pooler + (size_t)row0 * Dc);
    nv_float4*    o_base = (nv_float4*)(out + (size_t)row0 * Dc);

    // ---- issue ALL pooler loads first: 12 independent 1KB loads in flight ----
    float4 t[ROWS_PER_WAVE][3];
#pragma unroll
    for (int r = 0; r < ROWS_PER_WAVE; ++r)
#pragma unroll
        for (int j = 0; j < 3; ++j)
            t[r][j] = p_base[r * (Dc / 4) + lane + j * 64];

    // ---- per-b prologue (overlaps with pooler loads in flight): xt, s11, S1 ----
    float4 xt[3];
    float s11 = 0.f, S1 = 0.f;
#pragma unroll
    for (int j = 0; j < 3; ++j) {
        const int idx4 = lane + j * 64;
        float4 w0 = W0_4[idx4];
        float4 w1 = W1_4[idx4];
        float4 bd = b_4[idx4];
        float4 x;
        x.x = fmaf(e0, w0.x, fmaf(e1, w1.x, bd.x));
        x.y = fmaf(e0, w0.y, fmaf(e1, w1.y, bd.y));
        x.z = fmaf(e0, w0.z, fmaf(e1, w1.z, bd.z));
        x.w = fmaf(e0, w0.w, fmaf(e1, w1.w, bd.w));
        xt[j] = x;
        s11 += x.x*x.x + x.y*x.y + x.z*x.z + x.w*x.w;
        S1  += x.x + x.y + x.z + x.w;
    }

    // ---- per-row partial sums as loads land ----
    float s00[ROWS_PER_WAVE], s01[ROWS_PER_WAVE], S0[ROWS_PER_WAVE];
#pragma unroll
    for (int r = 0; r < ROWS_PER_WAVE; ++r) {
        float a0 = 0.f, a1 = 0.f, a2 = 0.f;
#pragma unroll
        for (int j = 0; j < 3; ++j) {
            const float4 p = t[r][j];
            a0 += p.x*p.x + p.y*p.y + p.z*p.z + p.w*p.w;
            a1 += p.x*xt[j].x + p.y*xt[j].y + p.z*xt[j].z + p.w*xt[j].w;
            a2 += p.x + p.y + p.z + p.w;
        }
        s00[r] = a0; s01[r] = a1; S0[r] = a2;
    }

    // ---- joint butterfly: 6 steps, 14 interleaved independent chains ----
#pragma unroll
    for (int off = 32; off > 0; off >>= 1) {
        s11 += __shfl_xor(s11, off);
        S1  += __shfl_xor(S1,  off);
#pragma unroll
        for (int r = 0; r < ROWS_PER_WAVE; ++r) {
            s00[r] += __shfl_xor(s00[r], off);
            s01[r] += __shfl_xor(s01[r], off);
            S0[r]  += __shfl_xor(S0[r],  off);
        }
    }

    // ---- deferred broadcast loads (L1/L2-hot): latency hides under softmax ----
    float4 gm[3], bt[3];
#pragma unroll
    for (int j = 0; j < 3; ++j) {
        gm[j] = g_4[lane + j * 64];
        bt[j] = be_4[lane + j * 64];
    }

    // ---- 4 independent softmax + LN-scalar chains ----
    const float invD = 1.f / (float)Dc;
    float ascale[ROWS_PER_WAVE], cscale[ROWS_PER_WAVE], mshift[ROWS_PER_WAVE];
#pragma unroll
    for (int r = 0; r < ROWS_PER_WAVE; ++r) {
        // Two 2-way softmaxes (max-subtracted: s00 ~ O(768), naive exp overflows).
        const float m0  = fmaxf(s00[r], s01[r]);
        const float a00 = __expf(s00[r] - m0);
        const float a01 = __expf(s01[r] - m0);
        const float r0  = 1.f / (a00 + a01);
        const float m1  = fmaxf(s01[r], s11);
        const float a10 = __expf(s01[r] - m1);
        const float a11 = __expf(s11 - m1);
        const float r1  = 1.f / (a10 + a11);
        const float w0s = a00 * r0 + a10 * r1;        // weight on pooler
        const float w1s = a01 * r0 + a11 * r1;        // weight on xt

        const float mean = (w0s * S0[r] + w1s * S1) * invD;
        const float ex2  = (w0s*w0s*s00[r] + 2.f*w0s*w1s*s01[r] + w1s*w1s*s11) * invD;
        const float var  = ex2 - mean * mean;
        const float rstd = rsqrtf(var + LN_EPS);

        ascale[r] = w0s * rstd;
        cscale[r] = w1s * rstd;
        mshift[r] = mean * rstd;
    }

    // ---- epilogue: (a*p + (c*xt - m))*gm + bt, 12 NT stores ----
#pragma unroll
    for (int r = 0; r < ROWS_PER_WAVE; ++r) {
        const float a = ascale[r], c = cscale[r], m = mshift[r];
        nv_float4* orow4 = o_base + (size_t)r * (Dc / 4);
#pragma unroll
        for (int j = 0; j < 3; ++j) {
            nv_float4 o;
            o.x = fmaf(gm[j].x, fmaf(a, t[r][j].x, fmaf(c, xt[j].x, -m)), bt[j].x);
            o.y = fmaf(gm[j].y, fmaf(a, t[r][j].y, fmaf(c, xt[j].y, -m)), bt[j].y);
            o.z = fmaf(gm[j].z, fmaf(a, t[r][j].z, fmaf(c, xt[j].z, -m)), bt[j].z);
            o.w = fmaf(gm[j].w, fmaf(a, t[r][j].w, fmaf(c, xt[j].w, -m)), bt[j].w);
            __builtin_nontemporal_store(o, &orow4[lane + j * 64]);
        }
    }
}

extern "C" void kernel_launch(void* const* d_in, const int* in_sizes, int n_in,
                              void* d_out, int out_size, void* d_ws, size_t ws_size,
                              hipStream_t stream) {
    const int*   ids       = (const int*)  d_in[0];
    const float* pooler    = (const float*)d_in[1];
    const float* emb_table = (const float*)d_in[2];
    const float* W_dense   = (const float*)d_in[3];
    const float* b_dense   = (const float*)d_in[4];
    const float* gamma     = (const float*)d_in[5];
    const float* beta      = (const float*)d_in[6];
    float* out = (float*)d_out;

    const int nrows = Bc * Lc;  // 32768
    hipLaunchKernelGGL(hier_attn_ln_kernel,
                       dim3(nrows / ROWS_PER_BLOCK), dim3(64 * WAVES_PER_BLOCK),
                       0, stream,
                       ids, pooler, emb_table, W_dense, b_dense, gamma, beta, out);
}